// Round 3
// baseline (673.256 us; speedup 1.0000x reference)
//
#include <hip/hip_runtime.h>
#include <math.h>

#define N_NODES 100000
#define N_EDGES 1600000
#define DIM 32
#define N_GROUPS 64
#define BN_EPS 1e-5f

// ---- monotone float<->uint encoding for atomic max on floats ----
__device__ __forceinline__ unsigned enc_f32(float f) {
    unsigned u = __float_as_uint(f);
    return (u & 0x80000000u) ? ~u : (u | 0x80000000u);
}
__device__ __forceinline__ float dec_f32(unsigned u) {
    return (u & 0x80000000u) ? __uint_as_float(u & 0x7FFFFFFFu) : __uint_as_float(~u);
}

// Fold BN into weights: Wf[k][j] = W[k][j]*scale_j, shift_j = (b_j - mean_j)*scale_j + beta_j
__global__ void fold_kernel(const float* __restrict__ lin_W, const float* __restrict__ lin_b,
                            const float* __restrict__ lin_gamma, const float* __restrict__ lin_beta,
                            const float* __restrict__ lin_mean, const float* __restrict__ lin_var,
                            const float* __restrict__ conv_W, const float* __restrict__ conv_b,
                            const float* __restrict__ conv_gamma, const float* __restrict__ conv_beta,
                            const float* __restrict__ conv_mean, const float* __restrict__ conv_var,
                            float* __restrict__ Wf,   // [5][32][32]
                            float* __restrict__ shf)  // [5][32]
{
    int l = blockIdx.x;      // 0..2 = lin, 3..4 = conv
    int t = threadIdx.x;     // 0..1023
    const float *W, *b, *gm, *bt, *mn, *vr;
    if (l < 3) {
        W = lin_W + l * DIM * DIM; b = lin_b + l * DIM; gm = lin_gamma + l * DIM;
        bt = lin_beta + l * DIM;   mn = lin_mean + l * DIM; vr = lin_var + l * DIM;
    } else {
        int c = l - 3;
        W = conv_W + c * DIM * DIM; b = conv_b + c * DIM; gm = conv_gamma + c * DIM;
        bt = conv_beta + c * DIM;   mn = conv_mean + c * DIM; vr = conv_var + c * DIM;
    }
    int j = t & (DIM - 1);
    float scale = gm[j] / sqrtf(vr[j] + BN_EPS);
    Wf[l * DIM * DIM + t] = W[t] * scale;
    if (t < DIM) shf[l * DIM + t] = (b[t] - mn[t]) * scale + bt[t];
}

// ======================= CSR build (per call) =======================
// deg[d] = #incoming edges of node d
__global__ __launch_bounds__(256) void hist_kernel(const int* __restrict__ dst,
                                                   int* __restrict__ deg) {
    int e = blockIdx.x * 256 + threadIdx.x;     // grid exact: E/256
    atomicAdd(&deg[dst[e]], 1);
}

// cursor = exclusive prefix sum of deg. Single workgroup of 1024.
__global__ __launch_bounds__(1024) void scan_kernel(const int* __restrict__ deg,
                                                    int* __restrict__ cursor) {
    __shared__ int s[1024];
    int t = threadIdx.x;
    const int CH = (N_NODES + 1023) / 1024;     // 98
    int beg = t * CH;
    int end = beg + CH; if (end > N_NODES) end = N_NODES;
    int sum = 0;
    for (int i = beg; i < end; ++i) sum += deg[i];
    s[t] = sum;
    __syncthreads();
    for (int off = 1; off < 1024; off <<= 1) {
        int v = (t >= off) ? s[t - off] : 0;
        __syncthreads();
        s[t] += v;
        __syncthreads();
    }
    int run = (t == 0) ? 0 : s[t - 1];
    for (int i = beg; i < end; ++i) { cursor[i] = run; run += deg[i]; }
}

// esrc[pos] = src[e], grouped by dst. Advances cursor so that afterwards
// cursor[d] == ptr[d+1] (end of d's segment); beg of d = (d? cursor[d-1] : 0).
__global__ __launch_bounds__(256) void scatter_kernel(const int* __restrict__ src,
                                                      const int* __restrict__ dst,
                                                      int* __restrict__ cursor,
                                                      int* __restrict__ esrc) {
    int e = blockIdx.x * 256 + threadIdx.x;     // grid exact
    int pos = atomicAdd(&cursor[dst[e]], 1);
    esrc[pos] = src[e];
}

// ======================= pull-gather =======================
// One wave per dst node: hout[i] = x[i] + sum_{e in CSR(i)} x[esrc[e]].
// Lane layout: slot = lane>>3 (8 edge slots), c4 = (lane&7)*4 (float4 col chunk).
__global__ __launch_bounds__(256) void gather_kernel(
        const float* __restrict__ x,
        const int* __restrict__ esrc,
        const int* __restrict__ cursor,   // post-scatter: cursor[i] == end(i)
        float* __restrict__ hout)
{
    int node = (blockIdx.x * 256 + threadIdx.x) >> 6;   // grid exact: N waves
    int lane = threadIdx.x & 63;
    int slot = lane >> 3;
    int c4   = (lane & 7) * 4;
    int beg = (node == 0) ? 0 : cursor[node - 1];
    int end = cursor[node];
    float4 acc = make_float4(0.f, 0.f, 0.f, 0.f);
    for (int e = beg + slot; e < end; e += 8) {
        int s = esrc[e];
        const float4 v = *(const float4*)(x + (size_t)s * DIM + c4);
        acc.x += v.x; acc.y += v.y; acc.z += v.z; acc.w += v.w;
    }
#pragma unroll
    for (int off = 8; off < 64; off <<= 1) {
        acc.x += __shfl_xor(acc.x, off, 64);
        acc.y += __shfl_xor(acc.y, off, 64);
        acc.z += __shfl_xor(acc.z, off, 64);
        acc.w += __shfl_xor(acc.w, off, 64);
    }
    if (slot == 0) {
        const float4 xv = *(const float4*)(x + (size_t)node * DIM + c4);
        float4 r = make_float4(acc.x + xv.x, acc.y + xv.y, acc.z + xv.z, acc.w + xv.w);
        *(float4*)(hout + (size_t)node * DIM + c4) = r;
    }
}

// z = elu(h @ Wf + shift); Z accumulate; hierarchical segment-max (batch sorted).
#define TILES_PER_BLOCK 16
template <bool FIRST>
__global__ __launch_bounds__(256) void lin_mlp_kernel(
        const float* __restrict__ h,       // [N,32]
        const float* __restrict__ Wf,      // [32,32] folded
        const float* __restrict__ shf,     // [32]
        const int* __restrict__ batch,     // [N] sorted
        const float* __restrict__ lw_ptr,  // scalar layer weight
        float* __restrict__ Zout,          // [N,32]
        unsigned* __restrict__ segmax)     // [G,32] encoded
{
    __shared__ float Wl[DIM * DIM];
    __shared__ float sh[DIM];
    __shared__ float hl[8 * DIM];
    int t = threadIdx.x;
    for (int i = t; i < DIM * DIM; i += 256) Wl[i] = Wf[i];
    if (t < DIM) sh[t] = shf[t];
    __syncthreads();

    int rl = t >> 5;
    int col = t & 31;
    float lw = lw_ptr[0];
    int row0 = blockIdx.x * (TILES_PER_BLOCK * 8);

    float m = 0.f;
    int gcur = -1;

    for (int tile = 0; tile < TILES_PER_BLOCK; ++tile) {
        int rbase = row0 + tile * 8;
        if (rbase >= N_NODES) break;
        int base = rbase * DIM;
        __syncthreads();
        hl[t] = h[base + t];
        __syncthreads();

        float acc = sh[col];
#pragma unroll
        for (int k = 0; k < DIM; ++k) acc += hl[rl * DIM + k] * Wl[k * DIM + col];
        float z = acc > 0.f ? acc : expm1f(acc);
        float zw = lw * z;
        if (FIRST) Zout[base + t] = zw;
        else       Zout[base + t] += zw;

        float segval = FIRST ? z : zw;
        int g = batch[rbase + rl];
        if (g != gcur) {
            if (gcur >= 0) atomicMax(&segmax[gcur * DIM + col], enc_f32(m));
            gcur = g;
            m = segval;
        } else {
            m = fmaxf(m, segval);
        }
    }
    if (gcur >= 0) atomicMax(&segmax[gcur * DIM + col], enc_f32(m));
}

// x' = elu(h @ Wf + shift), h already = x + agg
__global__ __launch_bounds__(256) void conv_mlp_kernel(
        const float* __restrict__ h,
        const float* __restrict__ Wf,
        const float* __restrict__ shf,
        float* __restrict__ out)
{
    __shared__ float Wl[DIM * DIM];
    __shared__ float sh[DIM];
    __shared__ float hl[8 * DIM];
    int t = threadIdx.x;
    for (int i = t; i < DIM * DIM; i += 256) Wl[i] = Wf[i];
    if (t < DIM) sh[t] = shf[t];
    int base = blockIdx.x * 8 * DIM;
    hl[t] = h[base + t];
    __syncthreads();

    int rl = t >> 5;
    int col = t & 31;
    float acc = sh[col];
#pragma unroll
    for (int k = 0; k < DIM; ++k) acc += hl[rl * DIM + k] * Wl[k * DIM + col];
    out[base + rl * DIM + col] = acc > 0.f ? acc : expm1f(acc);
}

// out[g][j] += decode(segmax[g][j])
__global__ void add_out_kernel(const unsigned* __restrict__ segmax, float* __restrict__ out) {
    int t = blockIdx.x * blockDim.x + threadIdx.x;  // 2048
    out[t] += dec_f32(segmax[t]);
}

extern "C" void kernel_launch(void* const* d_in, const int* in_sizes, int n_in,
                              void* d_out, int out_size, void* d_ws, size_t ws_size,
                              hipStream_t stream) {
    const float* x0        = (const float*)d_in[0];
    const int*   ei        = (const int*)d_in[1];     // (2,E): row0=src, row1=dst
    const int*   batch     = (const int*)d_in[2];
    const float* lw        = (const float*)d_in[3];
    const float* lin_W     = (const float*)d_in[4];
    const float* lin_b     = (const float*)d_in[5];
    const float* lin_gamma = (const float*)d_in[6];
    const float* lin_beta  = (const float*)d_in[7];
    const float* lin_mean  = (const float*)d_in[8];
    const float* lin_var   = (const float*)d_in[9];
    const float* conv_W    = (const float*)d_in[10];
    const float* conv_b    = (const float*)d_in[11];
    const float* conv_gamma= (const float*)d_in[12];
    const float* conv_beta = (const float*)d_in[13];
    const float* conv_mean = (const float*)d_in[14];
    const float* conv_var  = (const float*)d_in[15];

    float* out  = (float*)d_out;                 // [G*32]
    float* Z    = out + N_GROUPS * DIM;          // [N*32]
    float* xout = Z + (size_t)N_NODES * DIM;     // [N*32]

    char* p = (char*)d_ws;
    float*    hbuf  = (float*)p;    p += (size_t)N_NODES * DIM * sizeof(float);
    float*    xbuf  = (float*)p;    p += (size_t)N_NODES * DIM * sizeof(float);
    int*      esrc  = (int*)p;      p += (size_t)N_EDGES * sizeof(int);
    int*      deg   = (int*)p;      p += (size_t)N_NODES * sizeof(int);
    int*      cursor= (int*)p;      p += (size_t)N_NODES * sizeof(int);
    unsigned* segmx = (unsigned*)p; p += N_GROUPS * DIM * sizeof(unsigned);
    float*    Wf    = (float*)p;    p += 5 * DIM * DIM * sizeof(float);
    float*    shf   = (float*)p;    p += 5 * DIM * sizeof(float);

    const int* src = ei;
    const int* dst = ei + N_EDGES;

    const int mlp_blocks  = N_NODES / 8;                                  // 12500
    const int linm_blocks = (N_NODES + TILES_PER_BLOCK * 8 - 1) / (TILES_PER_BLOCK * 8);
    const int edge_blocks = N_EDGES / 256;                                // 6250
    const int gath_blocks = N_NODES / 4;                                  // 25000 (4 waves/block)

    hipMemsetAsync(out, 0, N_GROUPS * DIM * sizeof(float), stream);
    hipMemsetAsync(deg, 0, (size_t)N_NODES * sizeof(int), stream);
    fold_kernel<<<5, 1024, 0, stream>>>(lin_W, lin_b, lin_gamma, lin_beta, lin_mean, lin_var,
                                        conv_W, conv_b, conv_gamma, conv_beta, conv_mean, conv_var,
                                        Wf, shf);

    // ---- CSR build (once per call, reused by both conv layers) ----
    hist_kernel<<<edge_blocks, 256, 0, stream>>>(dst, deg);
    scan_kernel<<<1, 1024, 0, stream>>>(deg, cursor);
    scatter_kernel<<<edge_blocks, 256, 0, stream>>>(src, dst, cursor, esrc);

    // ---- layer 0 ----
    hipMemsetAsync(segmx, 0, N_GROUPS * DIM * sizeof(unsigned), stream);
    lin_mlp_kernel<true><<<linm_blocks, 256, 0, stream>>>(x0, Wf, shf, batch, lw, Z, segmx);
    add_out_kernel<<<8, 256, 0, stream>>>(segmx, out);

    // ---- layer 1 ----
    gather_kernel<<<gath_blocks, 256, 0, stream>>>(x0, esrc, cursor, hbuf);
    conv_mlp_kernel<<<mlp_blocks, 256, 0, stream>>>(hbuf, Wf + 3 * DIM * DIM, shf + 3 * DIM, xbuf);
    hipMemsetAsync(segmx, 0, N_GROUPS * DIM * sizeof(unsigned), stream);
    lin_mlp_kernel<false><<<linm_blocks, 256, 0, stream>>>(xbuf, Wf + 1 * DIM * DIM, shf + 1 * DIM,
                                                           batch, lw + 1, Z, segmx);
    add_out_kernel<<<8, 256, 0, stream>>>(segmx, out);

    // ---- layer 2 ----
    gather_kernel<<<gath_blocks, 256, 0, stream>>>(xbuf, esrc, cursor, hbuf);
    conv_mlp_kernel<<<mlp_blocks, 256, 0, stream>>>(hbuf, Wf + 4 * DIM * DIM, shf + 4 * DIM, xout);
    hipMemsetAsync(segmx, 0, N_GROUPS * DIM * sizeof(unsigned), stream);
    lin_mlp_kernel<false><<<linm_blocks, 256, 0, stream>>>(xout, Wf + 2 * DIM * DIM, shf + 2 * DIM,
                                                           batch, lw + 2, Z, segmx);
    add_out_kernel<<<8, 256, 0, stream>>>(segmx, out);
}

// Round 4
// 512.455 us; speedup vs baseline: 1.3138x; 1.3138x over previous
//
#include <hip/hip_runtime.h>
#include <math.h>

#define N_NODES 100000
#define N_EDGES 1600000
#define DIM 32
#define N_GROUPS 64
#define BN_EPS 1e-5f

#define SCAN_CHUNK 1024
#define SCAN_BLOCKS ((N_NODES + SCAN_CHUNK - 1) / SCAN_CHUNK)   // 98

// ---- monotone float<->uint encoding for atomic max on floats ----
__device__ __forceinline__ unsigned enc_f32(float f) {
    unsigned u = __float_as_uint(f);
    return (u & 0x80000000u) ? ~u : (u | 0x80000000u);
}
__device__ __forceinline__ float dec_f32(unsigned u) {
    return (u & 0x80000000u) ? __uint_as_float(u & 0x7FFFFFFFu) : __uint_as_float(~u);
}

// Fold BN into weights: Wf[k][j] = W[k][j]*scale_j, shift_j = (b_j - mean_j)*scale_j + beta_j
__global__ void fold_kernel(const float* __restrict__ lin_W, const float* __restrict__ lin_b,
                            const float* __restrict__ lin_gamma, const float* __restrict__ lin_beta,
                            const float* __restrict__ lin_mean, const float* __restrict__ lin_var,
                            const float* __restrict__ conv_W, const float* __restrict__ conv_b,
                            const float* __restrict__ conv_gamma, const float* __restrict__ conv_beta,
                            const float* __restrict__ conv_mean, const float* __restrict__ conv_var,
                            float* __restrict__ Wf,   // [5][32][32]
                            float* __restrict__ shf)  // [5][32]
{
    int l = blockIdx.x;      // 0..2 = lin, 3..4 = conv
    int t = threadIdx.x;     // 0..1023
    const float *W, *b, *gm, *bt, *mn, *vr;
    if (l < 3) {
        W = lin_W + l * DIM * DIM; b = lin_b + l * DIM; gm = lin_gamma + l * DIM;
        bt = lin_beta + l * DIM;   mn = lin_mean + l * DIM; vr = lin_var + l * DIM;
    } else {
        int c = l - 3;
        W = conv_W + c * DIM * DIM; b = conv_b + c * DIM; gm = conv_gamma + c * DIM;
        bt = conv_beta + c * DIM;   mn = conv_mean + c * DIM; vr = conv_var + c * DIM;
    }
    int j = t & (DIM - 1);
    float scale = gm[j] / sqrtf(vr[j] + BN_EPS);
    Wf[l * DIM * DIM + t] = W[t] * scale;
    if (t < DIM) shf[l * DIM + t] = (b[t] - mn[t]) * scale + bt[t];
}

// ======================= CSR build (per call) =======================
// deg[d] = #incoming edges of node d
__global__ __launch_bounds__(256) void hist_kernel(const int* __restrict__ dst,
                                                   int* __restrict__ deg) {
    int e = blockIdx.x * 256 + threadIdx.x;     // grid exact: E/256
    atomicAdd(&deg[dst[e]], 1);
}

// Phase A: per-block local exclusive scan of 1024 elems (4/thread), emit block sum.
__global__ __launch_bounds__(256) void scan_block_kernel(const int* __restrict__ deg,
                                                         int* __restrict__ cursor,
                                                         int* __restrict__ bsum) {
    __shared__ int s[256];
    int t = threadIdx.x;
    int base = blockIdx.x * SCAN_CHUNK + t * 4;
    int4 v = make_int4(0, 0, 0, 0);
    if (base + 3 < N_NODES) v = *(const int4*)(deg + base);
    else if (base < N_NODES) {
        v.x = deg[base];
        if (base + 1 < N_NODES) v.y = deg[base + 1];
        if (base + 2 < N_NODES) v.z = deg[base + 2];
    }
    int tsum = v.x + v.y + v.z + v.w;
    s[t] = tsum;
    __syncthreads();
    for (int off = 1; off < 256; off <<= 1) {
        int u = (t >= off) ? s[t - off] : 0;
        __syncthreads();
        s[t] += u;
        __syncthreads();
    }
    int excl = s[t] - tsum;
    if (t == 255) bsum[blockIdx.x] = s[255];
    if (base < N_NODES) {
        int4 o;
        o.x = excl;
        o.y = o.x + v.x;
        o.z = o.y + v.y;
        o.w = o.z + v.z;
        if (base + 3 < N_NODES) *(int4*)(cursor + base) = o;
        else {
            cursor[base] = o.x;
            if (base + 1 < N_NODES) cursor[base + 1] = o.y;
            if (base + 2 < N_NODES) cursor[base + 2] = o.z;
        }
    }
}

// Phase B: exclusive scan of the block sums (SCAN_BLOCKS <= 128), in place.
__global__ __launch_bounds__(128) void scan_bsum_kernel(int* __restrict__ bsum) {
    __shared__ int s[128];
    int t = threadIdx.x;
    int v = (t < SCAN_BLOCKS) ? bsum[t] : 0;
    s[t] = v;
    __syncthreads();
    for (int off = 1; off < 128; off <<= 1) {
        int u = (t >= off) ? s[t - off] : 0;
        __syncthreads();
        s[t] += u;
        __syncthreads();
    }
    if (t < SCAN_BLOCKS) bsum[t] = s[t] - v;    // exclusive
}

// Phase C: add block offsets.
__global__ __launch_bounds__(256) void scan_add_kernel(int* __restrict__ cursor,
                                                       const int* __restrict__ bsum) {
    int base = blockIdx.x * SCAN_CHUNK + threadIdx.x * 4;
    int off = bsum[blockIdx.x];
    if (base + 3 < N_NODES) {
        int4 v = *(int4*)(cursor + base);
        v.x += off; v.y += off; v.z += off; v.w += off;
        *(int4*)(cursor + base) = v;
    } else if (base < N_NODES) {
        cursor[base] += off;
        if (base + 1 < N_NODES) cursor[base + 1] += off;
        if (base + 2 < N_NODES) cursor[base + 2] += off;
    }
}

// esrc[pos] = src[e], grouped by dst. Advances cursor so that afterwards
// cursor[d] == end(d); beg(d) = (d ? cursor[d-1] : 0).
__global__ __launch_bounds__(256) void scatter_kernel(const int* __restrict__ src,
                                                      const int* __restrict__ dst,
                                                      int* __restrict__ cursor,
                                                      int* __restrict__ esrc) {
    int e = blockIdx.x * 256 + threadIdx.x;     // grid exact
    int pos = atomicAdd(&cursor[dst[e]], 1);
    esrc[pos] = src[e];
}

// ======================= pull-gather =======================
// One wave per dst node: hout[i] = x[i] + sum_{e in CSR(i)} x[esrc[e]].
__global__ __launch_bounds__(256) void gather_kernel(
        const float* __restrict__ x,
        const int* __restrict__ esrc,
        const int* __restrict__ cursor,   // post-scatter: cursor[i] == end(i)
        float* __restrict__ hout)
{
    int node = (blockIdx.x * 256 + threadIdx.x) >> 6;   // grid exact: N waves
    int lane = threadIdx.x & 63;
    int slot = lane >> 3;
    int c4   = (lane & 7) * 4;
    int beg = (node == 0) ? 0 : cursor[node - 1];
    int end = cursor[node];
    float4 acc = make_float4(0.f, 0.f, 0.f, 0.f);
    for (int e = beg + slot; e < end; e += 8) {
        int s = esrc[e];
        const float4 v = *(const float4*)(x + (size_t)s * DIM + c4);
        acc.x += v.x; acc.y += v.y; acc.z += v.z; acc.w += v.w;
    }
#pragma unroll
    for (int off = 8; off < 64; off <<= 1) {
        acc.x += __shfl_xor(acc.x, off, 64);
        acc.y += __shfl_xor(acc.y, off, 64);
        acc.z += __shfl_xor(acc.z, off, 64);
        acc.w += __shfl_xor(acc.w, off, 64);
    }
    if (slot == 0) {
        const float4 xv = *(const float4*)(x + (size_t)node * DIM + c4);
        float4 r = make_float4(acc.x + xv.x, acc.y + xv.y, acc.z + xv.z, acc.w + xv.w);
        *(float4*)(hout + (size_t)node * DIM + c4) = r;
    }
}

// z = elu(h @ Wf + shift); Z accumulate; hierarchical segment-max (batch sorted).
#define TILES_PER_BLOCK 16
template <bool FIRST>
__global__ __launch_bounds__(256) void lin_mlp_kernel(
        const float* __restrict__ h,       // [N,32]
        const float* __restrict__ Wf,      // [32,32] folded
        const float* __restrict__ shf,     // [32]
        const int* __restrict__ batch,     // [N] sorted
        const float* __restrict__ lw_ptr,  // scalar layer weight
        float* __restrict__ Zout,          // [N,32]
        unsigned* __restrict__ segmax)     // [G,32] encoded
{
    __shared__ float Wl[DIM * DIM];
    __shared__ float sh[DIM];
    __shared__ float hl[8 * DIM];
    int t = threadIdx.x;
    for (int i = t; i < DIM * DIM; i += 256) Wl[i] = Wf[i];
    if (t < DIM) sh[t] = shf[t];
    __syncthreads();

    int rl = t >> 5;
    int col = t & 31;
    float lw = lw_ptr[0];
    int row0 = blockIdx.x * (TILES_PER_BLOCK * 8);

    float m = 0.f;
    int gcur = -1;

    for (int tile = 0; tile < TILES_PER_BLOCK; ++tile) {
        int rbase = row0 + tile * 8;
        if (rbase >= N_NODES) break;
        int base = rbase * DIM;
        __syncthreads();
        hl[t] = h[base + t];
        __syncthreads();

        float acc = sh[col];
#pragma unroll
        for (int k = 0; k < DIM; ++k) acc += hl[rl * DIM + k] * Wl[k * DIM + col];
        float z = acc > 0.f ? acc : expm1f(acc);
        float zw = lw * z;
        if (FIRST) Zout[base + t] = zw;
        else       Zout[base + t] += zw;

        float segval = FIRST ? z : zw;
        int g = batch[rbase + rl];
        if (g != gcur) {
            if (gcur >= 0) atomicMax(&segmax[gcur * DIM + col], enc_f32(m));
            gcur = g;
            m = segval;
        } else {
            m = fmaxf(m, segval);
        }
    }
    if (gcur >= 0) atomicMax(&segmax[gcur * DIM + col], enc_f32(m));
}

// x' = elu(h @ Wf + shift), h already = x + agg
__global__ __launch_bounds__(256) void conv_mlp_kernel(
        const float* __restrict__ h,
        const float* __restrict__ Wf,
        const float* __restrict__ shf,
        float* __restrict__ out)
{
    __shared__ float Wl[DIM * DIM];
    __shared__ float sh[DIM];
    __shared__ float hl[8 * DIM];
    int t = threadIdx.x;
    for (int i = t; i < DIM * DIM; i += 256) Wl[i] = Wf[i];
    if (t < DIM) sh[t] = shf[t];
    int base = blockIdx.x * 8 * DIM;
    hl[t] = h[base + t];
    __syncthreads();

    int rl = t >> 5;
    int col = t & 31;
    float acc = sh[col];
#pragma unroll
    for (int k = 0; k < DIM; ++k) acc += hl[rl * DIM + k] * Wl[k * DIM + col];
    out[base + rl * DIM + col] = acc > 0.f ? acc : expm1f(acc);
}

// out[g][j] += decode(segmax[g][j])
__global__ void add_out_kernel(const unsigned* __restrict__ segmax, float* __restrict__ out) {
    int t = blockIdx.x * blockDim.x + threadIdx.x;  // 2048
    out[t] += dec_f32(segmax[t]);
}

extern "C" void kernel_launch(void* const* d_in, const int* in_sizes, int n_in,
                              void* d_out, int out_size, void* d_ws, size_t ws_size,
                              hipStream_t stream) {
    const float* x0        = (const float*)d_in[0];
    const int*   ei        = (const int*)d_in[1];     // (2,E): row0=src, row1=dst
    const int*   batch     = (const int*)d_in[2];
    const float* lw        = (const float*)d_in[3];
    const float* lin_W     = (const float*)d_in[4];
    const float* lin_b     = (const float*)d_in[5];
    const float* lin_gamma = (const float*)d_in[6];
    const float* lin_beta  = (const float*)d_in[7];
    const float* lin_mean  = (const float*)d_in[8];
    const float* lin_var   = (const float*)d_in[9];
    const float* conv_W    = (const float*)d_in[10];
    const float* conv_b    = (const float*)d_in[11];
    const float* conv_gamma= (const float*)d_in[12];
    const float* conv_beta = (const float*)d_in[13];
    const float* conv_mean = (const float*)d_in[14];
    const float* conv_var  = (const float*)d_in[15];

    float* out  = (float*)d_out;                 // [G*32]
    float* Z    = out + N_GROUPS * DIM;          // [N*32]
    float* xout = Z + (size_t)N_NODES * DIM;     // [N*32]

    char* p = (char*)d_ws;
    float*    hbuf  = (float*)p;    p += (size_t)N_NODES * DIM * sizeof(float);
    float*    xbuf  = (float*)p;    p += (size_t)N_NODES * DIM * sizeof(float);
    int*      esrc  = (int*)p;      p += (size_t)N_EDGES * sizeof(int);
    int*      deg   = (int*)p;      p += (size_t)N_NODES * sizeof(int);
    int*      cursor= (int*)p;      p += (size_t)N_NODES * sizeof(int);
    int*      bsum  = (int*)p;      p += 128 * sizeof(int);
    unsigned* segmx = (unsigned*)p; p += N_GROUPS * DIM * sizeof(unsigned);
    float*    Wf    = (float*)p;    p += 5 * DIM * DIM * sizeof(float);
    float*    shf   = (float*)p;    p += 5 * DIM * sizeof(float);

    const int* src = ei;
    const int* dst = ei + N_EDGES;

    const int mlp_blocks  = N_NODES / 8;                                  // 12500
    const int linm_blocks = (N_NODES + TILES_PER_BLOCK * 8 - 1) / (TILES_PER_BLOCK * 8);
    const int edge_blocks = N_EDGES / 256;                                // 6250
    const int gath_blocks = N_NODES / 4;                                  // 25000 (4 waves/block)

    hipMemsetAsync(out, 0, N_GROUPS * DIM * sizeof(float), stream);
    hipMemsetAsync(deg, 0, (size_t)N_NODES * sizeof(int), stream);
    fold_kernel<<<5, 1024, 0, stream>>>(lin_W, lin_b, lin_gamma, lin_beta, lin_mean, lin_var,
                                        conv_W, conv_b, conv_gamma, conv_beta, conv_mean, conv_var,
                                        Wf, shf);

    // ---- CSR build (once per call, reused by both conv layers) ----
    hist_kernel<<<edge_blocks, 256, 0, stream>>>(dst, deg);
    scan_block_kernel<<<SCAN_BLOCKS, 256, 0, stream>>>(deg, cursor, bsum);
    scan_bsum_kernel<<<1, 128, 0, stream>>>(bsum);
    scan_add_kernel<<<SCAN_BLOCKS, 256, 0, stream>>>(cursor, bsum);
    scatter_kernel<<<edge_blocks, 256, 0, stream>>>(src, dst, cursor, esrc);

    // ---- layer 0 ----
    hipMemsetAsync(segmx, 0, N_GROUPS * DIM * sizeof(unsigned), stream);
    lin_mlp_kernel<true><<<linm_blocks, 256, 0, stream>>>(x0, Wf, shf, batch, lw, Z, segmx);
    add_out_kernel<<<8, 256, 0, stream>>>(segmx, out);

    // ---- layer 1 ----
    gather_kernel<<<gath_blocks, 256, 0, stream>>>(x0, esrc, cursor, hbuf);
    conv_mlp_kernel<<<mlp_blocks, 256, 0, stream>>>(hbuf, Wf + 3 * DIM * DIM, shf + 3 * DIM, xbuf);
    hipMemsetAsync(segmx, 0, N_GROUPS * DIM * sizeof(unsigned), stream);
    lin_mlp_kernel<false><<<linm_blocks, 256, 0, stream>>>(xbuf, Wf + 1 * DIM * DIM, shf + 1 * DIM,
                                                           batch, lw + 1, Z, segmx);
    add_out_kernel<<<8, 256, 0, stream>>>(segmx, out);

    // ---- layer 2 ----
    gather_kernel<<<gath_blocks, 256, 0, stream>>>(xbuf, esrc, cursor, hbuf);
    conv_mlp_kernel<<<mlp_blocks, 256, 0, stream>>>(hbuf, Wf + 4 * DIM * DIM, shf + 4 * DIM, xout);
    hipMemsetAsync(segmx, 0, N_GROUPS * DIM * sizeof(unsigned), stream);
    lin_mlp_kernel<false><<<linm_blocks, 256, 0, stream>>>(xout, Wf + 2 * DIM * DIM, shf + 2 * DIM,
                                                           batch, lw + 2, Z, segmx);
    add_out_kernel<<<8, 256, 0, stream>>>(segmx, out);
}